// Round 14
// baseline (79.975 us; speedup 1.0000x reference)
//
#include <hip/hip_runtime.h>
#include <math.h>

#define D 256
#define TWOD 512
#define BB 1024
#define NN 131072
#define LOG2E 1.4426950408889634f

typedef float v4f __attribute__((ext_vector_type(4)));

__device__ __forceinline__ v4f ldg_nt(const float* p, bool valid) {
  v4f z = {0.f, 0.f, 0.f, 0.f};
  if (valid) z = __builtin_nontemporal_load((const v4f*)p);
  return z;
}

__device__ __forceinline__ float dot4(v4f a, v4f b) {
  return fmaf(a.w, b.w, fmaf(a.z, b.z, fmaf(a.y, b.y, a.x * b.x)));
}

// ---------------- prep (unchanged)
__global__ __launch_bounds__(256) void prep_kernel(
    const float* __restrict__ Wq, const float* __restrict__ bq,
    const float* __restrict__ Wk, const float* __restrict__ Wv,
    const float* __restrict__ bv, const float* __restrict__ Wo,
    const float* __restrict__ bo, const int* __restrict__ bidx,
    float* __restrict__ Mt, float* __restrict__ WfT,
    float* __restrict__ bqt, float* __restrict__ cvec,
    int* __restrict__ offs) {
  const int blk = blockIdx.x;
  const int t = threadIdx.x;
  if (blk < 64) {
    __shared__ __align__(16) float part[4][4][D];   // 16 KB
    const int wq = t >> 6, lane = t & 63;
    const int d0 = blk * 4;
    v4f a0 = {0.f, 0.f, 0.f, 0.f}, a1 = a0, a2 = a0, a3 = a0;
    for (int ee = 0; ee < 64; ++ee) {
      const int e = wq * 64 + ee;
      const v4f wk4 = *(const v4f*)&Wk[(size_t)e * D + lane * 4];  // coalesced
      const float* wqr = Wq + (size_t)e * D + d0;                  // uniform -> sgpr
      a0 += wk4 * wqr[0];
      a1 += wk4 * wqr[1];
      a2 += wk4 * wqr[2];
      a3 += wk4 * wqr[3];
    }
    *(v4f*)&part[wq][0][lane * 4] = a0;
    *(v4f*)&part[wq][1][lane * 4] = a1;
    *(v4f*)&part[wq][2][lane * 4] = a2;
    *(v4f*)&part[wq][3][lane * 4] = a3;
    __syncthreads();
    #pragma unroll
    for (int r = 0; r < 4; ++r)
      Mt[(size_t)(d0 + r) * D + t] =
          part[0][r][t] + part[1][r][t] + part[2][r][t] + part[3][r][t];
  } else if (blk < 128) {
    const int h0 = (blk - 64) * 4;
    float a0 = 0.f, a1 = 0.f, a2 = 0.f, a3 = 0.f;
    for (int v = 0; v < D; ++v) {
      const float wo = Wo[(size_t)t * TWOD + D + v]; // per-lane own-row walk (L1)
      const float* wvr = Wv + (size_t)v * D + h0;    // uniform -> sgpr
      a0 = fmaf(wvr[0], wo, a0);
      a1 = fmaf(wvr[1], wo, a1);
      a2 = fmaf(wvr[2], wo, a2);
      a3 = fmaf(wvr[3], wo, a3);
    }
    WfT[(size_t)(D + h0 + 0) * D + t] = a0;
    WfT[(size_t)(D + h0 + 1) * D + t] = a1;
    WfT[(size_t)(D + h0 + 2) * D + t] = a2;
    WfT[(size_t)(D + h0 + 3) * D + t] = a3;
  } else if (blk < 144) {
    __shared__ float tile[64][65];
    const int b = blk - 128;
    const int r0 = (b >> 2) * 64, c0 = (b & 3) * 64;
    const int lane = t & 63, sr = t >> 6;
    #pragma unroll 4
    for (int rr = 0; rr < 16; ++rr) {
      const int r = rr * 4 + sr;
      tile[r][lane] = Wo[(size_t)(r0 + r) * TWOD + c0 + lane];
    }
    __syncthreads();
    #pragma unroll 4
    for (int rr = 0; rr < 16; ++rr) {
      const int r = rr * 4 + sr;
      WfT[(size_t)(c0 + r) * D + r0 + lane] = tile[lane][r];
    }
  } else if (blk == 144) {
    float a = 0.f;
    for (int e = 0; e < D; ++e)
      a = fmaf(Wk[(size_t)e * D + t], bq[e], a);
    bqt[t] = a;
  } else if (blk == 145) {
    float a = bo[t];
    for (int v = 0; v < D; ++v)
      a = fmaf(Wo[(size_t)t * TWOD + D + v], bv[v], a);
    cvec[t] = a;
  } else {
    const int i = (blk - 146) * 256 + t;
    if (i >= NN) return;
    const int b1 = bidx[i];
    const int b2 = (i + 1 < NN) ? bidx[i + 1] : BB;
    if (i == 0) {
      for (int b = 0; b <= b1; ++b) offs[b] = 0;
    }
    for (int b = b1 + 1; b <= b2; ++b) offs[b] = i + 1;
  }
}

// ---------------- fused f (identical to R13)
__global__ __launch_bounds__(1024) void f_kernel(
    const float* __restrict__ H, const float* __restrict__ V,
    const float* __restrict__ Mt, const float* __restrict__ bqt,
    const int* __restrict__ offs, const float* __restrict__ WfT,
    const float* __restrict__ cvec, float* __restrict__ out) {
  __shared__ __align__(16) char smem[32768 + 4096 + 8192];
  float (*partq)[4][D] = (float(*)[4][D])smem;
  float (*ss)[D] = (float(*)[D])smem;
  float (*part)[4][D] = (float(*)[4][D])smem;
  float* Vs  = (float*)(smem + 32768);
  float* Us2 = (float*)(smem + 36864);
  __shared__ float sm[16], sd[16];
  __shared__ int soff[5];

  const int t = threadIdx.x;
  const int wave = t >> 6, lane = t & 63;
  const int blk = blockIdx.x;
  const int b0 = blk * 4;

  if (t < 5) soff[t] = offs[b0 + t];
  {
    const int i = t >> 8, d = t & 255;
    Vs[i * 256 + d] = V[(size_t)(b0 + i) * D + d];
  }
  __syncthreads();

  const int ib = wave >> 2, ph = wave & 3;
  const int start = soff[ib];
  const int cnt = soff[ib + 1] - start;
  const int ck = (cnt + 3) >> 2;
  const int s0 = start + min(cnt, ph * ck);
  const int e0 = start + min(cnt, (ph + 1) * ck);
  int n = s0;
  v4f c0 = ldg_nt(H + (size_t)n * D + lane * 4, n < e0);
  v4f c1 = ldg_nt(H + (size_t)(n + 1) * D + lane * 4, n + 1 < e0);
  v4f f0 = ldg_nt(H + (size_t)(n + 2) * D + lane * 4, n + 2 < e0);
  v4f f1 = ldg_nt(H + (size_t)(n + 3) * D + lane * 4, n + 3 < e0);

  {
    v4f a0 = {0.f, 0.f, 0.f, 0.f}, a1 = a0, a2 = a0, a3 = a0;
    const int db = wave * 16;
    #pragma unroll 4
    for (int dd = 0; dd < 16; ++dd) {
      const int d = db + dd;
      const v4f w4 = *(const v4f*)(Mt + (size_t)d * D + lane * 4);
      a0 += w4 * Vs[0 * 256 + d];
      a1 += w4 * Vs[1 * 256 + d];
      a2 += w4 * Vs[2 * 256 + d];
      a3 += w4 * Vs[3 * 256 + d];
    }
    if (wave >= 8) {
      *(v4f*)&partq[wave - 8][0][lane * 4] = a0;
      *(v4f*)&partq[wave - 8][1][lane * 4] = a1;
      *(v4f*)&partq[wave - 8][2][lane * 4] = a2;
      *(v4f*)&partq[wave - 8][3][lane * 4] = a3;
    }
    __syncthreads();
    if (wave < 8) {
      v4f p0 = *(const v4f*)&partq[wave][0][lane * 4];
      v4f p1 = *(const v4f*)&partq[wave][1][lane * 4];
      v4f p2 = *(const v4f*)&partq[wave][2][lane * 4];
      v4f p3 = *(const v4f*)&partq[wave][3][lane * 4];
      *(v4f*)&partq[wave][0][lane * 4] = a0 + p0;
      *(v4f*)&partq[wave][1][lane * 4] = a1 + p1;
      *(v4f*)&partq[wave][2][lane * 4] = a2 + p2;
      *(v4f*)&partq[wave][3][lane * 4] = a3 + p3;
    }
  }
  __syncthreads();

  v4f q4 = *(const v4f*)(bqt + lane * 4);
  #pragma unroll
  for (int w = 0; w < 8; ++w) q4 += *(const v4f*)&partq[w][ib][lane * 4];
  __syncthreads();

  float m = -1e30f, den = 0.f;
  v4f acc = {0.f, 0.f, 0.f, 0.f};
  {
    const float SC = 0.0625f * LOG2E;
    const int odd = lane & 1;
    while (n < e0) {
      const int nn = n + 4;
      v4f g0 = ldg_nt(H + (size_t)nn * D + lane * 4, nn < e0);
      v4f g1 = ldg_nt(H + (size_t)(nn + 1) * D + lane * 4, nn + 1 < e0);

      const float d0 = dot4(c0, q4);
      const float d1 = dot4(c1, q4);
      const float mine = odd ? d1 : d0;
      const float oth  = odd ? d0 : d1;
      float s = mine + __shfl_xor(oth, 1);
      s += __shfl_xor(s, 2);
      s += __shfl_xor(s, 4);
      s += __shfl_xor(s, 8);
      s += __shfl_xor(s, 16);
      s += __shfl_xor(s, 32);
      const float sc = (n + odd < e0) ? s * SC : -1e30f;

      const float mm = fmaxf(sc, __shfl_xor(sc, 1));
      const float nm = fmaxf(m, mm);
      const float f = exp2f(m - nm);
      const float w = exp2f(sc - nm);
      const float wx = __shfl_xor(w, 1);
      const float wr0 = odd ? wx : w;
      const float wr1 = odd ? w : wx;
      den = fmaf(den, f, w + wx);
      acc = acc * f + c0 * wr0 + c1 * wr1;
      m = nm;

      c0 = f0; c1 = f1; f0 = g0; f1 = g1; n += 2;
    }
  }
  *(v4f*)&ss[wave][lane * 4] = acc;
  if (lane == 0) { sm[wave] = m; sd[wave] = den; }
  __syncthreads();

  {
    const int i = t >> 8, d = t & 255;
    const int w0 = i * 4;
    const float m0 = sm[w0], m1 = sm[w0 + 1], m2 = sm[w0 + 2], m3 = sm[w0 + 3];
    const float M = fmaxf(fmaxf(m0, m1), fmaxf(m2, m3));
    const float f0m = exp2f(m0 - M), f1m = exp2f(m1 - M);
    const float f2m = exp2f(m2 - M), f3m = exp2f(m3 - M);
    const float Dn = sd[w0] * f0m + sd[w0 + 1] * f1m + sd[w0 + 2] * f2m + sd[w0 + 3] * f3m;
    const float inv = (Dn > 0.f) ? (1.f / Dn) : 0.f;
    const float sv = (ss[w0][d] * f0m + ss[w0 + 1][d] * f1m +
                      ss[w0 + 2][d] * f2m + ss[w0 + 3][d] * f3m) * inv;
    Us2[d * 4 + i] = Vs[i * 256 + d];
    Us2[(D + d) * 4 + i] = sv;
  }
  __syncthreads();

  {
    v4f a0 = {0.f, 0.f, 0.f, 0.f}, a1 = a0, a2 = a0, a3 = a0;
    const int kb = wave * 32;
    #pragma unroll 4
    for (int kk = 0; kk < 32; ++kk) {
      const int k = kb + kk;
      const v4f w4 = *(const v4f*)(WfT + (size_t)k * D + lane * 4);
      const v4f u4 = *(const v4f*)&Us2[k * 4];
      a0 += w4 * u4.x; a1 += w4 * u4.y; a2 += w4 * u4.z; a3 += w4 * u4.w;
    }
    if (wave >= 8) {
      *(v4f*)&part[wave - 8][0][lane * 4] = a0;
      *(v4f*)&part[wave - 8][1][lane * 4] = a1;
      *(v4f*)&part[wave - 8][2][lane * 4] = a2;
      *(v4f*)&part[wave - 8][3][lane * 4] = a3;
    }
    __syncthreads();
    if (wave < 8) {
      v4f p0 = *(const v4f*)&part[wave][0][lane * 4];
      v4f p1 = *(const v4f*)&part[wave][1][lane * 4];
      v4f p2 = *(const v4f*)&part[wave][2][lane * 4];
      v4f p3 = *(const v4f*)&part[wave][3][lane * 4];
      *(v4f*)&part[wave][0][lane * 4] = a0 + p0;
      *(v4f*)&part[wave][1][lane * 4] = a1 + p1;
      *(v4f*)&part[wave][2][lane * 4] = a2 + p2;
      *(v4f*)&part[wave][3][lane * 4] = a3 + p3;
    }
  }
  __syncthreads();
  {
    const int i = t >> 8, d = t & 255;
    const int bb2 = b0 + i;
    float s = cvec[d];
    #pragma unroll
    for (int w = 0; w < 8; ++w) s += part[w][i][d];
    const int c = soff[i + 1] - soff[i];
    out[(size_t)bb2 * D + d] = (c > 0) ? s : Us2[d * 4 + i];
  }
}

extern "C" void kernel_launch(void* const* d_in, const int* in_sizes, int n_in,
                              void* d_out, int out_size, void* d_ws, size_t ws_size,
                              hipStream_t stream) {
  const float* V   = (const float*)d_in[0];
  const float* H   = (const float*)d_in[1];
  const int* bidx  = (const int*)d_in[2];
  const float* Wq  = (const float*)d_in[3];
  const float* bq  = (const float*)d_in[4];
  const float* Wk  = (const float*)d_in[5];
  const float* Wv  = (const float*)d_in[7];
  const float* bv  = (const float*)d_in[8];
  const float* Wo  = (const float*)d_in[9];
  const float* bo  = (const float*)d_in[10];
  float* out = (float*)d_out;

  float* ws  = (float*)d_ws;
  float* Mt  = ws;                       // 256*256
  float* WfT = Mt + D * D;               // 512*256
  float* bqt = WfT + TWOD * D;           // 256
  float* cv  = bqt + D;                  // 256
  int* offs  = (int*)(cv + D);           // 1025

  hipLaunchKernelGGL(prep_kernel, dim3(658), dim3(256), 0, stream,
                     Wq, bq, Wk, Wv, bv, Wo, bo, bidx,
                     Mt, WfT, bqt, cv, offs);
  // ATTRIBUTION PROBE: f launched twice (idempotent). f_dur = dur(R14) - dur(R13).
  hipLaunchKernelGGL(f_kernel, dim3(BB / 4), dim3(1024), 0, stream,
                     H, V, Mt, bqt, offs, WfT, cv, out);
  hipLaunchKernelGGL(f_kernel, dim3(BB / 4), dim3(1024), 0, stream,
                     H, V, Mt, bqt, offs, WfT, cv, out);
}